// Round 14
// baseline (488.899 us; speedup 1.0000x reference)
//
#include <hip/hip_runtime.h>
#include <hip/hip_bf16.h>
#include <math.h>

// Problem constants (B=2, T=S=2048, D=3072, H=16, hd=192, d_c=1024)
#define BB 2
#define TT 2048
#define DD 3072
#define NH 16
#define HD 192
#define DC 1024

typedef __attribute__((ext_vector_type(8))) short bh8;    // 8 bf16 = 4 VGPR
typedef __attribute__((ext_vector_type(4))) float f32x4;  // MFMA accum
typedef unsigned int u32;

__device__ __forceinline__ short f2b(float f) {
  __hip_bfloat16 h = __float2bfloat16(f);  // RNE
  return *reinterpret_cast<short*>(&h);
}

// async global->LDS, 16B per lane; LDS dest = wave-uniform base + lane*16
__device__ __forceinline__ void gload16(const void* g, void* lds) {
  __builtin_amdgcn_global_load_lds(
      (const __attribute__((address_space(1))) u32*)g,
      (__attribute__((address_space(3))) u32*)lds, 16, 0, 0);
}

// ---------------------------------------------------------------------------
// fused fp32 -> bf16 cast for 4 buffers, block-uniform range dispatch
// ranges: x 6144 | Wq 4608 | Wkv 1536 | Wuv 1536 blocks (8 elems/thread)
// ---------------------------------------------------------------------------
__global__ __launch_bounds__(256) void cast4_k(
    const float* __restrict__ x, short* __restrict__ xb,
    const float* __restrict__ wq, short* __restrict__ wqb,
    const float* __restrict__ wkv, short* __restrict__ wkvb,
    const float* __restrict__ wuv, short* __restrict__ wuvb) {
  const int blk = blockIdx.x;
  const float* in;
  short* out;
  size_t base;
  if (blk < 6144) {
    in = x; out = xb; base = (size_t)blk;
  } else if (blk < 10752) {
    in = wq; out = wqb; base = (size_t)(blk - 6144);
  } else if (blk < 12288) {
    in = wkv; out = wkvb; base = (size_t)(blk - 10752);
  } else {
    in = wuv; out = wuvb; base = (size_t)(blk - 12288);
  }
  size_t i = (base * 256 + threadIdx.x) * 8;
  float4 v0 = *(const float4*)&in[i];
  float4 v1 = *(const float4*)&in[i + 4];
  bh8 o;
  o[0] = f2b(v0.x); o[1] = f2b(v0.y); o[2] = f2b(v0.z); o[3] = f2b(v0.w);
  o[4] = f2b(v1.x); o[5] = f2b(v1.y); o[6] = f2b(v1.z); o[7] = f2b(v1.w);
  *(bh8*)&out[i] = o;
}

// ---------------------------------------------------------------------------
// fp32 -> bf16 cast, 8 elems/thread, exact grid cover
// ---------------------------------------------------------------------------
__global__ __launch_bounds__(256) void cast_f2b_k(const float* __restrict__ in,
                                                  short* __restrict__ out) {
  size_t i = ((size_t)blockIdx.x * 256 + threadIdx.x) * 8;
  float4 v0 = *(const float4*)&in[i];
  float4 v1 = *(const float4*)&in[i + 4];
  bh8 o;
  o[0] = f2b(v0.x); o[1] = f2b(v0.y); o[2] = f2b(v0.z); o[3] = f2b(v0.w);
  o[4] = f2b(v1.x); o[5] = f2b(v1.y); o[6] = f2b(v1.z); o[7] = f2b(v1.w);
  *(bh8*)&out[i] = o;
}

// ---------------------------------------------------------------------------
// sum of two fp32 partials -> bf16 (deterministic split-K fixup)
// ---------------------------------------------------------------------------
__global__ __launch_bounds__(256) void sum_cast_k(const float* __restrict__ p0,
                                                  const float* __restrict__ p1,
                                                  short* __restrict__ out) {
  size_t i = ((size_t)blockIdx.x * 256 + threadIdx.x) * 8;
  float4 a0 = *(const float4*)&p0[i];
  float4 a1 = *(const float4*)&p0[i + 4];
  float4 b0 = *(const float4*)&p1[i];
  float4 b1 = *(const float4*)&p1[i + 4];
  bh8 o;
  o[0] = f2b(a0.x + b0.x); o[1] = f2b(a0.y + b0.y);
  o[2] = f2b(a0.z + b0.z); o[3] = f2b(a0.w + b0.w);
  o[4] = f2b(a1.x + b1.x); o[5] = f2b(a1.y + b1.y);
  o[6] = f2b(a1.z + b1.z); o[7] = f2b(a1.w + b1.w);
  *(bh8*)&out[i] = o;
}

// ---------------------------------------------------------------------------
// fp32 [R][C] -> bf16 [C][R] cast-transpose (64x64 LDS tiles)
// ---------------------------------------------------------------------------
__global__ __launch_bounds__(256) void castT_f2b_k(const float* __restrict__ in,
                                                   short* __restrict__ out,
                                                   int R, int C) {
  __shared__ float t[64][65];
  const int cx = blockIdx.x * 64, ry = blockIdx.y * 64;
  const int tid = threadIdx.x, lx = tid & 15, ly = tid >> 4;
#pragma unroll
  for (int i = 0; i < 4; ++i) {
    int r = ly + i * 16;
    float4 v = *(const float4*)&in[(size_t)(ry + r) * C + cx + lx * 4];
    t[r][lx * 4 + 0] = v.x; t[r][lx * 4 + 1] = v.y;
    t[r][lx * 4 + 2] = v.z; t[r][lx * 4 + 3] = v.w;
  }
  __syncthreads();
#pragma unroll
  for (int i = 0; i < 4; ++i) {
    int c = ly + i * 16;  // original column = output row
    ushort4 v;
    v.x = (unsigned short)f2b(t[lx * 4 + 0][c]);
    v.y = (unsigned short)f2b(t[lx * 4 + 1][c]);
    v.z = (unsigned short)f2b(t[lx * 4 + 2][c]);
    v.w = (unsigned short)f2b(t[lx * 4 + 3][c]);
    *(ushort4*)&out[(size_t)(cx + c) * R + ry + lx * 4] = v;
  }
}

// ---------------------------------------------------------------------------
// bf16 GEMM (m97 skeleton, BK=64): C[M][N] = A[M][Klen] @ Bt[N][Klen]^T
// 128x128 tile, 4 waves (2x2), 4x4 16x16x32 frags/wave, 2 k-halves/iter.
// lda/ldb row strides; blockIdx.z = split-K slice (A/Bt advance z*Klen,
// Cout advances z*zoff_bytes; deterministic partials, no atomics).
// OUTMODE: 0 = fp32 row-major; 1 = bf16 row-major;
//          3 = fused kv split: n0<3072 -> v-half scattered into
//              Cout2 = vT[b][col][t] (lane stores ushort4 of 4 consecutive
//              t -> wave fills 128B lines), n0>=3072 -> k-half row-major
//              bf16 into Cout at stride DD (col-3072). Branch block-uniform.
// T1: bijective XCD-aware block swizzle (nwg%8==0 everywhere).
// ---------------------------------------------------------------------------
template <int OUTMODE, bool BIAS>
__global__ __launch_bounds__(256) void gemm_bf16(
    const short* __restrict__ A, const short* __restrict__ Bt,
    const float* __restrict__ bias, void* __restrict__ Cout,
    void* __restrict__ Cout2,
    int M, int N, int Klen, int lda, int ldb, size_t zoff_bytes) {
  __shared__ short As[8192];  // [128][64] bf16, swizzled 8-chunk rows
  __shared__ short Bs[8192];
  const int tid = threadIdx.x;
  const int w = tid >> 6, l = tid & 63, lm = l & 15, lg = l >> 4;
  const int wr = w >> 1, wc = w & 1;

  const int bz = blockIdx.z;
  A += (size_t)bz * Klen;
  Bt += (size_t)bz * Klen;
  Cout = (void*)((char*)Cout + (size_t)bz * zoff_bytes);

  // XCD swizzle: XCD k gets contiguous chunk of the flat grid (m157/m204)
  const int nwg = gridDim.x * gridDim.y;
  const int flat = blockIdx.y * gridDim.x + blockIdx.x;
  const int wgid = (flat & 7) * (nwg >> 3) + (flat >> 3);
  const int m0 = (wgid / gridDim.x) * 128, n0 = (wgid % gridDim.x) * 128;

  f32x4 acc[4][4] = {};

  for (int k0 = 0; k0 < Klen; k0 += 64) {
    __syncthreads();
#pragma unroll
    for (int c = 0; c < 4; ++c) {
      int p = c * 256 + w * 64 + l;  // chunk index 0..1023
      int row = p >> 3, kc = p & 7;
      int g = kc ^ (row & 7);        // swizzled source chunk (8B elems)
      gload16(&A[(size_t)(m0 + row) * lda + k0 + g * 8],
              &As[(c * 256 + w * 64) * 8]);
      gload16(&Bt[(size_t)(n0 + row) * ldb + k0 + g * 8],
              &Bs[(c * 256 + w * 64) * 8]);
    }
    __syncthreads();

#pragma unroll
    for (int kh = 0; kh < 2; ++kh) {
      bh8 a[4], b[4];
#pragma unroll
      for (int mi = 0; mi < 4; ++mi) {
        int r = wr * 64 + mi * 16 + lm;
        a[mi] = *(const bh8*)&As[r * 64 + (((kh * 4 + lg) ^ (r & 7)) << 3)];
      }
#pragma unroll
      for (int ni = 0; ni < 4; ++ni) {
        int r = wc * 64 + ni * 16 + lm;
        b[ni] = *(const bh8*)&Bs[r * 64 + (((kh * 4 + lg) ^ (r & 7)) << 3)];
      }
#pragma unroll
      for (int mi = 0; mi < 4; ++mi)
#pragma unroll
        for (int ni = 0; ni < 4; ++ni)
          acc[mi][ni] = __builtin_amdgcn_mfma_f32_16x16x32_bf16(
              a[mi], b[ni], acc[mi][ni], 0, 0, 0);
    }
  }

  // epilogue: C layout col=lane&15, row=(lane>>4)*4+reg   [m89]
#pragma unroll
  for (int mi = 0; mi < 4; ++mi) {
#pragma unroll
    for (int ni = 0; ni < 4; ++ni) {
      int row = m0 + wr * 64 + mi * 16 + lg * 4;
      int col = n0 + wc * 64 + ni * 16 + lm;
      float bi = 0.f;
      if (BIAS) bi = bias[col];
      if (OUTMODE == 3) {
        if (n0 < 3072) {
          // v-half: vT[(b*DD + col)*TT + t], t = row&2047, b = row>>11
          int b = row >> 11, t = row & 2047;
          ushort4 o4;
          o4.x = (unsigned short)f2b(acc[mi][ni][0]);
          o4.y = (unsigned short)f2b(acc[mi][ni][1]);
          o4.z = (unsigned short)f2b(acc[mi][ni][2]);
          o4.w = (unsigned short)f2b(acc[mi][ni][3]);
          *(ushort4*)&((short*)Cout2)[((size_t)(b * DD + col)) * TT + t] = o4;
        } else {
#pragma unroll
          for (int r = 0; r < 4; ++r)
            ((short*)Cout)[(size_t)(row + r) * DD + (col - 3072)] =
                f2b(acc[mi][ni][r]);
        }
      } else {
#pragma unroll
        for (int r = 0; r < 4; ++r) {
          float v = acc[mi][ni][r] + bi;
          if (OUTMODE == 1)
            ((short*)Cout)[(size_t)(row + r) * N + col] = f2b(v);
          else
            ((float*)Cout)[(size_t)(row + r) * N + col] = v;
        }
      }
    }
  }
}

// ---------------------------------------------------------------------------
// LayerNorm over d_c=1024; input = cpre0 + cpre1 (split-K partials, fixed
// summation order -> deterministic). Writes fp32 (tuple out) + bf16 copy.
// ---------------------------------------------------------------------------
__global__ __launch_bounds__(256) void ln_k(const float* __restrict__ cp0,
                                            const float* __restrict__ cp1,
                                            const float* __restrict__ g,
                                            const float* __restrict__ bta,
                                            float* __restrict__ o32,
                                            short* __restrict__ o16) {
  const int row = blockIdx.x;
  const int tid = threadIdx.x;
  __shared__ float red1[4];
  __shared__ float red2[4];

  float4 va = *(const float4*)&cp0[(size_t)row * DC + tid * 4];
  float4 vb = *(const float4*)&cp1[(size_t)row * DC + tid * 4];
  float4 v;
  v.x = va.x + vb.x; v.y = va.y + vb.y; v.z = va.z + vb.z; v.w = va.w + vb.w;
  float s = v.x + v.y + v.z + v.w;
#pragma unroll
  for (int mk = 32; mk; mk >>= 1) s += __shfl_xor(s, mk, 64);
  if ((tid & 63) == 0) red1[tid >> 6] = s;
  __syncthreads();
  float mu = (red1[0] + red1[1] + red1[2] + red1[3]) * (1.f / DC);

  float dx = v.x - mu, dy = v.y - mu, dz = v.z - mu, dw = v.w - mu;
  float s2 = dx * dx + dy * dy + dz * dz + dw * dw;
#pragma unroll
  for (int mk = 32; mk; mk >>= 1) s2 += __shfl_xor(s2, mk, 64);
  if ((tid & 63) == 0) red2[tid >> 6] = s2;
  __syncthreads();
  float var = (red2[0] + red2[1] + red2[2] + red2[3]) * (1.f / DC);
  float rs = rsqrtf(var + 1e-5f);

  float4 gg = *(const float4*)&g[tid * 4];
  float4 bb = *(const float4*)&bta[tid * 4];
  float4 o;
  o.x = dx * rs * gg.x + bb.x;
  o.y = dy * rs * gg.y + bb.y;
  o.z = dz * rs * gg.z + bb.z;
  o.w = dw * rs * gg.w + bb.w;
  *(float4*)&o32[(size_t)row * DC + tid * 4] = o;
  ushort4 ob;
  ob.x = (unsigned short)f2b(o.x); ob.y = (unsigned short)f2b(o.y);
  ob.z = (unsigned short)f2b(o.z); ob.w = (unsigned short)f2b(o.w);
  *(ushort4*)&o16[(size_t)row * DC + tid * 4] = ob;
}

// ---------------------------------------------------------------------------
// Flash attention, bf16 MFMA — R3/R8/R9/R11-proven sync skeleton, plus
// defer-max (T13, THR=8) + log2-domain softmax, retried UNDER the VGPR pin:
// R10's 100us regression was the 132-VGPR occupancy cliff (no pin), not the
// algorithm (absmax was unchanged). __launch_bounds__(256,4) forces <=128.
// Block = 4 waves; each wave owns 16 q-rows (QBLK=64). KVBLK=64.
// Flat LPT grid; single-buffered gload_lds staging (56 KB -> 2 blocks/CU).
// ---------------------------------------------------------------------------
__global__ __launch_bounds__(256, 4) void attn_mfma(
    const short* __restrict__ xb, const short* __restrict__ kf,
    const short* __restrict__ vT, short* __restrict__ ctx) {
  __shared__ short Ks[64 * 192];   // 24 KB (swizzled chunks)
  __shared__ short Vs[192 * 64];   // 24 KB (V^T tile: [d][kv], swizzled)
  __shared__ short Ps[4][16 * 64]; //  8 KB (per-wave P, chunk-swizzled)

  const int idx = blockIdx.x;
  const int qt = 31 - (idx >> 5);  // q-tile, heavy first (LPT)
  const int bh = idx & 31;
  const int h = bh & 15, b = bh >> 4;
  const int tid = threadIdx.x, w = tid >> 6, l = tid & 63;
  const int lm = l & 15, lg = l >> 4;
  const int qw0 = qt * 64 + w * 16;     // wave's q-row base
  const float QS2 = 0.10411756672f;     // log2(e)/sqrt(192)

  // Q fragments resident: rows qw0+lm, 6 k-frags
  bh8 qf[6];
  {
    const short* qrow = &xb[(size_t)(b * TT + qw0 + lm) * DD + h * HD];
#pragma unroll
    for (int kq = 0; kq < 6; ++kq)
      qf[kq] = *(const bh8*)&qrow[kq * 32 + lg * 8];
  }

  f32x4 o[12] = {};
  float mrun[4], lrun[4];
#pragma unroll
  for (int r = 0; r < 4; ++r) { mrun[r] = -INFINITY; lrun[r] = 0.f; }

  for (int st = 0; st <= qt; ++st) {
    const int s0 = st * 64;
    __syncthreads();
    // stage K [64][192] and V^T [192][64], 6 x 16B/lane each
#pragma unroll
    for (int c = 0; c < 6; ++c) {
      int p = c * 256 + w * 64 + l;  // 0..1535
      {
        int krow = p / 24, kc = p - krow * 24;
        int g = kc ^ (krow & 7);
        gload16(&kf[(size_t)(b * TT + s0 + krow) * DD + h * HD + g * 8],
                &Ks[(c * 256 + w * 64) * 8]);
      }
      {
        int vrow = p >> 3, vc = p & 7;
        int gv = vc ^ (vrow & 7);
        gload16(&vT[(size_t)((b * NH + h) * HD + vrow) * TT + s0 + gv * 8],
                &Vs[(c * 256 + w * 64) * 8]);
      }
    }
    __syncthreads();  // compiler drains vmcnt(0) -> LDS ready

    // ---- QK^T: S[16 q][64 kv] as 4 nf frags ----
    f32x4 s[4] = {};
    __builtin_amdgcn_s_setprio(1);
#pragma unroll
    for (int nf = 0; nf < 4; ++nf) {
      const int krow = nf * 16 + lm;
      const short* kr = &Ks[krow * 192];
#pragma unroll
      for (int kq = 0; kq < 6; ++kq) {
        bh8 kb = *(const bh8*)&kr[(((kq * 4 + lg) ^ (krow & 7)) << 3)];
        s[nf] = __builtin_amdgcn_mfma_f32_16x16x32_bf16(qf[kq], kb, s[nf],
                                                        0, 0, 0);
      }
    }
    __builtin_amdgcn_s_setprio(0);

    // ---- online softmax, log2 domain, defer-max THR=8 (row = lg*4+r) ----
    float pv[4][4];  // [nf][r]
#pragma unroll
    for (int nf = 0; nf < 4; ++nf)
#pragma unroll
      for (int r = 0; r < 4; ++r) pv[nf][r] = s[nf][r] * QS2;
    if (st == qt) {  // diagonal tile: causal mask (wave-uniform branch)
#pragma unroll
      for (int nf = 0; nf < 4; ++nf)
#pragma unroll
        for (int r = 0; r < 4; ++r)
          if (nf * 16 + lm > w * 16 + lg * 4 + r) pv[nf][r] = -INFINITY;
    }
#pragma unroll
    for (int r = 0; r < 4; ++r) {
      float mt = fmaxf(fmaxf(pv[0][r], pv[1][r]), fmaxf(pv[2][r], pv[3][r]));
#pragma unroll
      for (int mk = 1; mk < 16; mk <<= 1) mt = fmaxf(mt, __shfl_xor(mt, mk));
      if (__any(mt > mrun[r] + 8.f)) {  // rescale only on real max growth
        float mnew = fmaxf(mrun[r], mt);
        float corr = exp2f(mrun[r] - mnew);  // exp2(-inf)=0 first tile
        mrun[r] = mnew;
        lrun[r] *= corr;
#pragma unroll
        for (int nf = 0; nf < 12; ++nf) o[nf][r] *= corr;
      }
      float ls = 0.f;
#pragma unroll
      for (int nf = 0; nf < 4; ++nf) {
        float p = exp2f(pv[nf][r] - mrun[r]);  // bounded by 2^8
        pv[nf][r] = p;
        ls += p;
      }
#pragma unroll
      for (int mk = 1; mk < 16; mk <<= 1) ls += __shfl_xor(ls, mk);
      lrun[r] += ls;
    }
    // write P (bf16) to per-wave LDS, chunk-XOR swizzled by row
#pragma unroll
    for (int nf = 0; nf < 4; ++nf)
#pragma unroll
      for (int r = 0; r < 4; ++r) {
        int prow = lg * 4 + r;
        int col = nf * 16 + lm;
        int sc = (((col >> 3) ^ (prow & 7)) << 3) + (col & 7);
        Ps[w][prow * 64 + sc] = f2b(pv[nf][r]);
      }
    // no barrier: Ps is same-wave write->read (lgkmcnt ordering)

    // ---- PV: O[16][192] += P[16][64] @ V[64][192] (B = V^T tile) ----
    bh8 pa0, pa1;
    {
      int prow = lm;
      pa0 = *(const bh8*)&Ps[w][prow * 64 + ((lg ^ (prow & 7)) << 3)];
      pa1 = *(const bh8*)&Ps[w][prow * 64 + (((4 + lg) ^ (prow & 7)) << 3)];
    }
    __builtin_amdgcn_s_setprio(1);
#pragma unroll
    for (int nf = 0; nf < 12; ++nf) {
      int drow = nf * 16 + lm;
      const short* vr = &Vs[drow * 64];
      bh8 vb0 = *(const bh8*)&vr[((lg ^ (drow & 7)) << 3)];
      bh8 vb1 = *(const bh8*)&vr[(((4 + lg) ^ (drow & 7)) << 3)];
      o[nf] = __builtin_amdgcn_mfma_f32_16x16x32_bf16(pa0, vb0, o[nf], 0, 0, 0);
      o[nf] = __builtin_amdgcn_mfma_f32_16x16x32_bf16(pa1, vb1, o[nf], 0, 0, 0);
    }
    __builtin_amdgcn_s_setprio(0);
  }

  // epilogue: ctx (bf16)
#pragma unroll
  for (int r = 0; r < 4; ++r) {
    float inv = 1.f / lrun[r];
    int row = qw0 + lg * 4 + r;
    short* cp = &ctx[(size_t)(b * TT + row) * DD + h * HD];
#pragma unroll
    for (int nf = 0; nf < 12; ++nf)
      cp[nf * 16 + lm] = f2b(o[nf][r] * inv);
  }
}

// ---------------------------------------------------------------------------
extern "C" void kernel_launch(void* const* d_in, const int* in_sizes, int n_in,
                              void* d_out, int out_size, void* d_ws,
                              size_t ws_size, hipStream_t stream) {
  const float* x    = (const float*)d_in[0];
  const float* Wq   = (const float*)d_in[1];
  const float* Wkv  = (const float*)d_in[2];
  const float* Wuk  = (const float*)d_in[3];
  const float* Wuv  = (const float*)d_in[4];
  const float* Wout = (const float*)d_in[5];
  const float* bout = (const float*)d_in[6];
  const float* lng  = (const float*)d_in[7];
  const float* lnb  = (const float*)d_in[8];

  float* out   = (float*)d_out;
  float* ckv32 = out + (size_t)BB * TT * DD;  // second tuple output (fp32)

  // workspace layout (bytes; high-water 169,869,312)
  char* W = (char*)d_ws;
  short* xb     = (short*)(W);                   // 25,165,824
  short* wbuf   = (short*)(W + 25165824);        // Wq_b then Wout_b
  short* wukT   = (short*)(W + 44040192);        //  6,291,456
  short* wkvb   = (short*)(W + 50331648);        //  6,291,456
  short* wuvb   = (short*)(W + 56623104);        //  6,291,456 (fused B rows 0-3071)
  short* akb    = (short*)(W + 62914560);        //  6,291,456 (fused B rows 3072-6143)
  float* cpre0  = (float*)(W + 69206016);        // 16,777,216 (dead after LN)
  short* ckvb   = (short*)(W + 85983232);        //  8,388,608
  short* kfullb = (short*)(W + 94371840);        // 25,165,824 (G45 k-half out)
  float* g1p0   = (float*)(W + 94371840);        // 12,582,912 (dead before G45)
  short* ctxb   = (short*)(W + 119537664);       // 25,165,824 (attn output)
  float* g1p1   = (float*)(W + 119537664);       // 12,582,912 (dead before attn)
  float* cpre1  = (float*)(W + 144703488);       // 16,777,216 (dead after LN)
  short* vTb    = (short*)(W + 144703488);       // 25,165,824 (G45 v-half, post-LN)
  const size_t G1_ZOFF = (size_t)(119537664 - 94371840);   // g1p1 - g1p0
  const size_t G2_ZOFF = (size_t)(144703488 - 69206016);   // cpre1 - cpre0

  // fused front casts: x, Wq, Wkv, Wuv (one launch) + Wuk cast-transpose
  cast4_k<<<13824, 256, 0, stream>>>(x, xb, Wq, wbuf, Wkv, wkvb, Wuv, wuvb);
  castT_f2b_k<<<dim3(16, 48), 256, 0, stream>>>(Wuk, wukT, 3072, 1024);

  // 1. absorbed_k = Wq @ Wuk  split-K x2: M=3072 N=1024 K=2x1536 -> fp32 x2
  gemm_bf16<0, false><<<dim3(8, 24, 2), 256, 0, stream>>>(
      wbuf, wukT, nullptr, g1p0, nullptr, 3072, 1024, 1536, 3072, 3072,
      G1_ZOFF);
  //    fixup: akb = f2b(g1p0 + g1p1)
  sum_cast_k<<<1536, 256, 0, stream>>>(g1p0, g1p1, akb);
  // Wout cast reuses wbuf after G1 (serial stream)
  cast_f2b_k<<<4608, 256, 0, stream>>>(Wout, wbuf);
  // 2. c_pre split-K x2: M=4096 N=1024 K=2x1536 -> fp32 partials
  gemm_bf16<0, false><<<dim3(8, 32, 2), 256, 0, stream>>>(
      xb, wkvb, nullptr, cpre0, nullptr, 4096, 1024, 1536, 3072, 3072,
      G2_ZOFF);
  // 3. LayerNorm(cpre0+cpre1) -> ckv (fp32 output) + ckvb (bf16)
  ln_k<<<4096, 256, 0, stream>>>(cpre0, cpre1, lng, lnb, ckv32, ckvb);
  // 4+5 fused: [v|k] = ckv @ [Wuv; absorbed_k]^T   M=4096 N=6144 K=1024
  //    cols 0-3071 -> vT scatter (Cout2), cols 3072-6143 -> kfull (Cout)
  gemm_bf16<3, false><<<dim3(48, 32), 256, 0, stream>>>(
      ckvb, wuvb, nullptr, kfullb, vTb, 4096, 6144, 1024, 1024, 1024, 0);
  // 6. flash attention -> ctx
  attn_mfma<<<1024, 256, 0, stream>>>(xb, kfullb, vTb, ctxb);
  // 7. out = ctx @ Wout^T + b_out       M=4096 N=3072 K=3072 -> fp32
  gemm_bf16<0, true><<<dim3(24, 32), 256, 0, stream>>>(
      ctxb, wbuf, bout, out, nullptr, 4096, 3072, 3072, 3072, 3072, 0);
}

// Round 15
// 388.770 us; speedup vs baseline: 1.2576x; 1.2576x over previous
//
#include <hip/hip_runtime.h>
#include <hip/hip_bf16.h>
#include <math.h>

// Problem constants (B=2, T=S=2048, D=3072, H=16, hd=192, d_c=1024)
#define BB 2
#define TT 2048
#define DD 3072
#define NH 16
#define HD 192
#define DC 1024

typedef __attribute__((ext_vector_type(8))) short bh8;    // 8 bf16 = 4 VGPR
typedef __attribute__((ext_vector_type(4))) float f32x4;  // MFMA accum
typedef unsigned int u32;

__device__ __forceinline__ short f2b(float f) {
  __hip_bfloat16 h = __float2bfloat16(f);  // RNE
  return *reinterpret_cast<short*>(&h);
}

// async global->LDS, 16B per lane; LDS dest = wave-uniform base + lane*16
__device__ __forceinline__ void gload16(const void* g, void* lds) {
  __builtin_amdgcn_global_load_lds(
      (const __attribute__((address_space(1))) u32*)g,
      (__attribute__((address_space(3))) u32*)lds, 16, 0, 0);
}

// ---------------------------------------------------------------------------
// fused fp32 -> bf16 cast for 4 buffers, block-uniform range dispatch
// ranges: x 6144 | Wq 4608 | Wkv 1536 | Wuv 1536 blocks (8 elems/thread)
// ---------------------------------------------------------------------------
__global__ __launch_bounds__(256) void cast4_k(
    const float* __restrict__ x, short* __restrict__ xb,
    const float* __restrict__ wq, short* __restrict__ wqb,
    const float* __restrict__ wkv, short* __restrict__ wkvb,
    const float* __restrict__ wuv, short* __restrict__ wuvb) {
  const int blk = blockIdx.x;
  const float* in;
  short* out;
  size_t base;
  if (blk < 6144) {
    in = x; out = xb; base = (size_t)blk;
  } else if (blk < 10752) {
    in = wq; out = wqb; base = (size_t)(blk - 6144);
  } else if (blk < 12288) {
    in = wkv; out = wkvb; base = (size_t)(blk - 10752);
  } else {
    in = wuv; out = wuvb; base = (size_t)(blk - 12288);
  }
  size_t i = (base * 256 + threadIdx.x) * 8;
  float4 v0 = *(const float4*)&in[i];
  float4 v1 = *(const float4*)&in[i + 4];
  bh8 o;
  o[0] = f2b(v0.x); o[1] = f2b(v0.y); o[2] = f2b(v0.z); o[3] = f2b(v0.w);
  o[4] = f2b(v1.x); o[5] = f2b(v1.y); o[6] = f2b(v1.z); o[7] = f2b(v1.w);
  *(bh8*)&out[i] = o;
}

// ---------------------------------------------------------------------------
// fp32 -> bf16 cast, 8 elems/thread, exact grid cover
// ---------------------------------------------------------------------------
__global__ __launch_bounds__(256) void cast_f2b_k(const float* __restrict__ in,
                                                  short* __restrict__ out) {
  size_t i = ((size_t)blockIdx.x * 256 + threadIdx.x) * 8;
  float4 v0 = *(const float4*)&in[i];
  float4 v1 = *(const float4*)&in[i + 4];
  bh8 o;
  o[0] = f2b(v0.x); o[1] = f2b(v0.y); o[2] = f2b(v0.z); o[3] = f2b(v0.w);
  o[4] = f2b(v1.x); o[5] = f2b(v1.y); o[6] = f2b(v1.z); o[7] = f2b(v1.w);
  *(bh8*)&out[i] = o;
}

// ---------------------------------------------------------------------------
// sum of two fp32 partials -> bf16 (deterministic split-K fixup)
// ---------------------------------------------------------------------------
__global__ __launch_bounds__(256) void sum_cast_k(const float* __restrict__ p0,
                                                  const float* __restrict__ p1,
                                                  short* __restrict__ out) {
  size_t i = ((size_t)blockIdx.x * 256 + threadIdx.x) * 8;
  float4 a0 = *(const float4*)&p0[i];
  float4 a1 = *(const float4*)&p0[i + 4];
  float4 b0 = *(const float4*)&p1[i];
  float4 b1 = *(const float4*)&p1[i + 4];
  bh8 o;
  o[0] = f2b(a0.x + b0.x); o[1] = f2b(a0.y + b0.y);
  o[2] = f2b(a0.z + b0.z); o[3] = f2b(a0.w + b0.w);
  o[4] = f2b(a1.x + b1.x); o[5] = f2b(a1.y + b1.y);
  o[6] = f2b(a1.z + b1.z); o[7] = f2b(a1.w + b1.w);
  *(bh8*)&out[i] = o;
}

// ---------------------------------------------------------------------------
// fp32 [R][C] -> bf16 [C][R] cast-transpose (64x64 LDS tiles)
// ---------------------------------------------------------------------------
__global__ __launch_bounds__(256) void castT_f2b_k(const float* __restrict__ in,
                                                   short* __restrict__ out,
                                                   int R, int C) {
  __shared__ float t[64][65];
  const int cx = blockIdx.x * 64, ry = blockIdx.y * 64;
  const int tid = threadIdx.x, lx = tid & 15, ly = tid >> 4;
#pragma unroll
  for (int i = 0; i < 4; ++i) {
    int r = ly + i * 16;
    float4 v = *(const float4*)&in[(size_t)(ry + r) * C + cx + lx * 4];
    t[r][lx * 4 + 0] = v.x; t[r][lx * 4 + 1] = v.y;
    t[r][lx * 4 + 2] = v.z; t[r][lx * 4 + 3] = v.w;
  }
  __syncthreads();
#pragma unroll
  for (int i = 0; i < 4; ++i) {
    int c = ly + i * 16;  // original column = output row
    ushort4 v;
    v.x = (unsigned short)f2b(t[lx * 4 + 0][c]);
    v.y = (unsigned short)f2b(t[lx * 4 + 1][c]);
    v.z = (unsigned short)f2b(t[lx * 4 + 2][c]);
    v.w = (unsigned short)f2b(t[lx * 4 + 3][c]);
    *(ushort4*)&out[(size_t)(cx + c) * R + ry + lx * 4] = v;
  }
}

// ---------------------------------------------------------------------------
// bf16 GEMM (m97 skeleton, BK=64): C[M][N] = A[M][Klen] @ Bt[N][Klen]^T
// 128x128 tile, 4 waves (2x2), 4x4 16x16x32 frags/wave, 2 k-halves/iter.
// lda/ldb row strides; blockIdx.z = split-K slice (A/Bt advance z*Klen,
// Cout advances z*zoff_bytes; deterministic partials, no atomics).
// OUTMODE: 0 = fp32 row-major; 1 = bf16 row-major;
//          3 = fused kv split: n0<3072 -> v-half scattered into
//              Cout2 = vT[b][col][t] (lane stores ushort4 of 4 consecutive
//              t -> wave fills 128B lines), n0>=3072 -> k-half row-major
//              bf16 into Cout at stride DD (col-3072). Branch block-uniform.
// T1: bijective XCD-aware block swizzle (nwg%8==0 everywhere).
// ---------------------------------------------------------------------------
template <int OUTMODE, bool BIAS>
__global__ __launch_bounds__(256) void gemm_bf16(
    const short* __restrict__ A, const short* __restrict__ Bt,
    const float* __restrict__ bias, void* __restrict__ Cout,
    void* __restrict__ Cout2,
    int M, int N, int Klen, int lda, int ldb, size_t zoff_bytes) {
  __shared__ short As[8192];  // [128][64] bf16, swizzled 8-chunk rows
  __shared__ short Bs[8192];
  const int tid = threadIdx.x;
  const int w = tid >> 6, l = tid & 63, lm = l & 15, lg = l >> 4;
  const int wr = w >> 1, wc = w & 1;

  const int bz = blockIdx.z;
  A += (size_t)bz * Klen;
  Bt += (size_t)bz * Klen;
  Cout = (void*)((char*)Cout + (size_t)bz * zoff_bytes);

  // XCD swizzle: XCD k gets contiguous chunk of the flat grid (m157/m204)
  const int nwg = gridDim.x * gridDim.y;
  const int flat = blockIdx.y * gridDim.x + blockIdx.x;
  const int wgid = (flat & 7) * (nwg >> 3) + (flat >> 3);
  const int m0 = (wgid / gridDim.x) * 128, n0 = (wgid % gridDim.x) * 128;

  f32x4 acc[4][4] = {};

  for (int k0 = 0; k0 < Klen; k0 += 64) {
    __syncthreads();
#pragma unroll
    for (int c = 0; c < 4; ++c) {
      int p = c * 256 + w * 64 + l;  // chunk index 0..1023
      int row = p >> 3, kc = p & 7;
      int g = kc ^ (row & 7);        // swizzled source chunk (8B elems)
      gload16(&A[(size_t)(m0 + row) * lda + k0 + g * 8],
              &As[(c * 256 + w * 64) * 8]);
      gload16(&Bt[(size_t)(n0 + row) * ldb + k0 + g * 8],
              &Bs[(c * 256 + w * 64) * 8]);
    }
    __syncthreads();

#pragma unroll
    for (int kh = 0; kh < 2; ++kh) {
      bh8 a[4], b[4];
#pragma unroll
      for (int mi = 0; mi < 4; ++mi) {
        int r = wr * 64 + mi * 16 + lm;
        a[mi] = *(const bh8*)&As[r * 64 + (((kh * 4 + lg) ^ (r & 7)) << 3)];
      }
#pragma unroll
      for (int ni = 0; ni < 4; ++ni) {
        int r = wc * 64 + ni * 16 + lm;
        b[ni] = *(const bh8*)&Bs[r * 64 + (((kh * 4 + lg) ^ (r & 7)) << 3)];
      }
#pragma unroll
      for (int mi = 0; mi < 4; ++mi)
#pragma unroll
        for (int ni = 0; ni < 4; ++ni)
          acc[mi][ni] = __builtin_amdgcn_mfma_f32_16x16x32_bf16(
              a[mi], b[ni], acc[mi][ni], 0, 0, 0);
    }
  }

  // epilogue: C layout col=lane&15, row=(lane>>4)*4+reg   [m89]
#pragma unroll
  for (int mi = 0; mi < 4; ++mi) {
#pragma unroll
    for (int ni = 0; ni < 4; ++ni) {
      int row = m0 + wr * 64 + mi * 16 + lg * 4;
      int col = n0 + wc * 64 + ni * 16 + lm;
      float bi = 0.f;
      if (BIAS) bi = bias[col];
      if (OUTMODE == 3) {
        if (n0 < 3072) {
          // v-half: vT[(b*DD + col)*TT + t], t = row&2047, b = row>>11
          int b = row >> 11, t = row & 2047;
          ushort4 o4;
          o4.x = (unsigned short)f2b(acc[mi][ni][0]);
          o4.y = (unsigned short)f2b(acc[mi][ni][1]);
          o4.z = (unsigned short)f2b(acc[mi][ni][2]);
          o4.w = (unsigned short)f2b(acc[mi][ni][3]);
          *(ushort4*)&((short*)Cout2)[((size_t)(b * DD + col)) * TT + t] = o4;
        } else {
#pragma unroll
          for (int r = 0; r < 4; ++r)
            ((short*)Cout)[(size_t)(row + r) * DD + (col - 3072)] =
                f2b(acc[mi][ni][r]);
        }
      } else {
#pragma unroll
        for (int r = 0; r < 4; ++r) {
          float v = acc[mi][ni][r] + bi;
          if (OUTMODE == 1)
            ((short*)Cout)[(size_t)(row + r) * N + col] = f2b(v);
          else
            ((float*)Cout)[(size_t)(row + r) * N + col] = v;
        }
      }
    }
  }
}

// ---------------------------------------------------------------------------
// LayerNorm over d_c=1024; input = cpre0 + cpre1 (split-K partials, fixed
// summation order -> deterministic). Writes fp32 (tuple out) + bf16 copy.
// ---------------------------------------------------------------------------
__global__ __launch_bounds__(256) void ln_k(const float* __restrict__ cp0,
                                            const float* __restrict__ cp1,
                                            const float* __restrict__ g,
                                            const float* __restrict__ bta,
                                            float* __restrict__ o32,
                                            short* __restrict__ o16) {
  const int row = blockIdx.x;
  const int tid = threadIdx.x;
  __shared__ float red1[4];
  __shared__ float red2[4];

  float4 va = *(const float4*)&cp0[(size_t)row * DC + tid * 4];
  float4 vb = *(const float4*)&cp1[(size_t)row * DC + tid * 4];
  float4 v;
  v.x = va.x + vb.x; v.y = va.y + vb.y; v.z = va.z + vb.z; v.w = va.w + vb.w;
  float s = v.x + v.y + v.z + v.w;
#pragma unroll
  for (int mk = 32; mk; mk >>= 1) s += __shfl_xor(s, mk, 64);
  if ((tid & 63) == 0) red1[tid >> 6] = s;
  __syncthreads();
  float mu = (red1[0] + red1[1] + red1[2] + red1[3]) * (1.f / DC);

  float dx = v.x - mu, dy = v.y - mu, dz = v.z - mu, dw = v.w - mu;
  float s2 = dx * dx + dy * dy + dz * dz + dw * dw;
#pragma unroll
  for (int mk = 32; mk; mk >>= 1) s2 += __shfl_xor(s2, mk, 64);
  if ((tid & 63) == 0) red2[tid >> 6] = s2;
  __syncthreads();
  float var = (red2[0] + red2[1] + red2[2] + red2[3]) * (1.f / DC);
  float rs = rsqrtf(var + 1e-5f);

  float4 gg = *(const float4*)&g[tid * 4];
  float4 bb = *(const float4*)&bta[tid * 4];
  float4 o;
  o.x = dx * rs * gg.x + bb.x;
  o.y = dy * rs * gg.y + bb.y;
  o.z = dz * rs * gg.z + bb.z;
  o.w = dw * rs * gg.w + bb.w;
  *(float4*)&o32[(size_t)row * DC + tid * 4] = o;
  ushort4 ob;
  ob.x = (unsigned short)f2b(o.x); ob.y = (unsigned short)f2b(o.y);
  ob.z = (unsigned short)f2b(o.z); ob.w = (unsigned short)f2b(o.w);
  *(ushort4*)&o16[(size_t)row * DC + tid * 4] = ob;
}

// ---------------------------------------------------------------------------
// Flash attention, bf16 MFMA — R3/R8/R9/R11/R13-proven structure (117-120us,
// VGPR 120). Block = 4 waves; each wave owns 16 q-rows (QBLK=64). KVBLK=64.
// Flat LPT grid: heavy (high-qt) blocks first. Single-buffered gload_lds
// staging (56 KB LDS -> 2 blocks/CU; cross-block TLP hides barrier drain).
// Constraints proven binding: <=128 VGPR (R4/R10/R14: crossing halves
// occupancy, ~2x cost; launch_bounds alone does NOT force it — the
// full-rescale __expf softmax is the only variant that fits); KVBLK=64
// (R12: 32 shrinks swizzle space -> 4-way bank conflicts + 2x tile costs);
// dedicated K buffer stride 3072 (R6: fused kvbuf stride 6144 over-fetches).
// ---------------------------------------------------------------------------
__global__ __launch_bounds__(256, 4) void attn_mfma(
    const short* __restrict__ xb, const short* __restrict__ kf,
    const short* __restrict__ vT, short* __restrict__ ctx) {
  __shared__ short Ks[64 * 192];   // 24 KB (swizzled chunks)
  __shared__ short Vs[192 * 64];   // 24 KB (V^T tile: [d][kv], swizzled)
  __shared__ short Ps[4][16 * 64]; //  8 KB (per-wave P, chunk-swizzled)

  const int idx = blockIdx.x;
  const int qt = 31 - (idx >> 5);  // q-tile, heavy first (LPT)
  const int bh = idx & 31;
  const int h = bh & 15, b = bh >> 4;
  const int tid = threadIdx.x, w = tid >> 6, l = tid & 63;
  const int lm = l & 15, lg = l >> 4;
  const int qw0 = qt * 64 + w * 16;       // wave's q-row base
  const float QS = 0.07216878364870323f;  // 1/sqrt(192)

  // Q fragments resident: rows qw0+lm, 6 k-frags
  bh8 qf[6];
  {
    const short* qrow = &xb[(size_t)(b * TT + qw0 + lm) * DD + h * HD];
#pragma unroll
    for (int kq = 0; kq < 6; ++kq)
      qf[kq] = *(const bh8*)&qrow[kq * 32 + lg * 8];
  }

  f32x4 o[12] = {};
  float mrun[4], lrun[4];
#pragma unroll
  for (int r = 0; r < 4; ++r) { mrun[r] = -INFINITY; lrun[r] = 0.f; }

  for (int st = 0; st <= qt; ++st) {
    const int s0 = st * 64;
    __syncthreads();
    // stage K [64][192] and V^T [192][64], 6 x 16B/lane each
#pragma unroll
    for (int c = 0; c < 6; ++c) {
      int p = c * 256 + w * 64 + l;  // 0..1535
      {
        int krow = p / 24, kc = p - krow * 24;
        int g = kc ^ (krow & 7);
        gload16(&kf[(size_t)(b * TT + s0 + krow) * DD + h * HD + g * 8],
                &Ks[(c * 256 + w * 64) * 8]);
      }
      {
        int vrow = p >> 3, vc = p & 7;
        int gv = vc ^ (vrow & 7);
        gload16(&vT[(size_t)((b * NH + h) * HD + vrow) * TT + s0 + gv * 8],
                &Vs[(c * 256 + w * 64) * 8]);
      }
    }
    __syncthreads();  // compiler drains vmcnt(0) -> LDS ready

    // ---- QK^T: S[16 q][64 kv] as 4 nf frags ----
    f32x4 s[4] = {};
    __builtin_amdgcn_s_setprio(1);
#pragma unroll
    for (int nf = 0; nf < 4; ++nf) {
      const int krow = nf * 16 + lm;
      const short* kr = &Ks[krow * 192];
#pragma unroll
      for (int kq = 0; kq < 6; ++kq) {
        bh8 kb = *(const bh8*)&kr[(((kq * 4 + lg) ^ (krow & 7)) << 3)];
        s[nf] = __builtin_amdgcn_mfma_f32_16x16x32_bf16(qf[kq], kb, s[nf],
                                                        0, 0, 0);
      }
    }
    __builtin_amdgcn_s_setprio(0);

    // ---- online softmax (row = lg*4+r) ----
    float pv[4][4];  // [nf][r]
#pragma unroll
    for (int nf = 0; nf < 4; ++nf)
#pragma unroll
      for (int r = 0; r < 4; ++r) pv[nf][r] = s[nf][r] * QS;
    if (st == qt) {  // diagonal tile: causal mask (wave-uniform branch)
#pragma unroll
      for (int nf = 0; nf < 4; ++nf)
#pragma unroll
        for (int r = 0; r < 4; ++r)
          if (nf * 16 + lm > w * 16 + lg * 4 + r) pv[nf][r] = -INFINITY;
    }
#pragma unroll
    for (int r = 0; r < 4; ++r) {
      float mt = fmaxf(fmaxf(pv[0][r], pv[1][r]), fmaxf(pv[2][r], pv[3][r]));
#pragma unroll
      for (int mk = 1; mk < 16; mk <<= 1) mt = fmaxf(mt, __shfl_xor(mt, mk));
      float mnew = fmaxf(mrun[r], mt);
      float corr = __expf(mrun[r] - mnew);  // exp(-inf)=0 first tile
      mrun[r] = mnew;
      float ls = 0.f;
#pragma unroll
      for (int nf = 0; nf < 4; ++nf) {
        float p = __expf(pv[nf][r] - mnew);
        pv[nf][r] = p;
        ls += p;
      }
#pragma unroll
      for (int mk = 1; mk < 16; mk <<= 1) ls += __shfl_xor(ls, mk);
      lrun[r] = lrun[r] * corr + ls;
#pragma unroll
      for (int nf = 0; nf < 12; ++nf) o[nf][r] *= corr;
    }
    // write P (bf16) to per-wave LDS, chunk-XOR swizzled by row
#pragma unroll
    for (int nf = 0; nf < 4; ++nf)
#pragma unroll
      for (int r = 0; r < 4; ++r) {
        int prow = lg * 4 + r;
        int col = nf * 16 + lm;
        int sc = (((col >> 3) ^ (prow & 7)) << 3) + (col & 7);
        Ps[w][prow * 64 + sc] = f2b(pv[nf][r]);
      }
    // no barrier: Ps is same-wave write->read (lgkmcnt ordering)

    // ---- PV: O[16][192] += P[16][64] @ V[64][192] (B = V^T tile) ----
    bh8 pa0, pa1;
    {
      int prow = lm;
      pa0 = *(const bh8*)&Ps[w][prow * 64 + ((lg ^ (prow & 7)) << 3)];
      pa1 = *(const bh8*)&Ps[w][prow * 64 + (((4 + lg) ^ (prow & 7)) << 3)];
    }
    __builtin_amdgcn_s_setprio(1);
#pragma unroll
    for (int nf = 0; nf < 12; ++nf) {
      int drow = nf * 16 + lm;
      const short* vr = &Vs[drow * 64];
      bh8 vb0 = *(const bh8*)&vr[((lg ^ (drow & 7)) << 3)];
      bh8 vb1 = *(const bh8*)&vr[(((4 + lg) ^ (drow & 7)) << 3)];
      o[nf] = __builtin_amdgcn_mfma_f32_16x16x32_bf16(pa0, vb0, o[nf], 0, 0, 0);
      o[nf] = __builtin_amdgcn_mfma_f32_16x16x32_bf16(pa1, vb1, o[nf], 0, 0, 0);
    }
    __builtin_amdgcn_s_setprio(0);
  }

  // epilogue: ctx (bf16)
#pragma unroll
  for (int r = 0; r < 4; ++r) {
    float inv = 1.f / lrun[r];
    int row = qw0 + lg * 4 + r;
    short* cp = &ctx[(size_t)(b * TT + row) * DD + h * HD];
#pragma unroll
    for (int nf = 0; nf < 12; ++nf)
      cp[nf * 16 + lm] = f2b(o[nf][r] * inv);
  }
}

// ---------------------------------------------------------------------------
extern "C" void kernel_launch(void* const* d_in, const int* in_sizes, int n_in,
                              void* d_out, int out_size, void* d_ws,
                              size_t ws_size, hipStream_t stream) {
  const float* x    = (const float*)d_in[0];
  const float* Wq   = (const float*)d_in[1];
  const float* Wkv  = (const float*)d_in[2];
  const float* Wuk  = (const float*)d_in[3];
  const float* Wuv  = (const float*)d_in[4];
  const float* Wout = (const float*)d_in[5];
  const float* bout = (const float*)d_in[6];
  const float* lng  = (const float*)d_in[7];
  const float* lnb  = (const float*)d_in[8];

  float* out   = (float*)d_out;
  float* ckv32 = out + (size_t)BB * TT * DD;  // second tuple output (fp32)

  // workspace layout (bytes; high-water 169,869,312)
  char* W = (char*)d_ws;
  short* xb     = (short*)(W);                   // 25,165,824
  short* wbuf   = (short*)(W + 25165824);        // Wq_b then Wout_b
  short* wukT   = (short*)(W + 44040192);        //  6,291,456
  short* wkvb   = (short*)(W + 50331648);        //  6,291,456
  short* wuvb   = (short*)(W + 56623104);        //  6,291,456 (fused B rows 0-3071)
  short* akb    = (short*)(W + 62914560);        //  6,291,456 (fused B rows 3072-6143)
  float* cpre0  = (float*)(W + 69206016);        // 16,777,216 (dead after LN)
  short* ckvb   = (short*)(W + 85983232);        //  8,388,608
  short* kfullb = (short*)(W + 94371840);        // 25,165,824 (G45 k-half out)
  float* g1p0   = (float*)(W + 94371840);        // 12,582,912 (dead before G45)
  short* ctxb   = (short*)(W + 119537664);       // 25,165,824 (attn output)
  float* g1p1   = (float*)(W + 119537664);       // 12,582,912 (dead before attn)
  float* cpre1  = (float*)(W + 144703488);       // 16,777,216 (dead after LN)
  short* vTb    = (short*)(W + 144703488);       // 25,165,824 (G45 v-half, post-LN)
  const size_t G1_ZOFF = (size_t)(119537664 - 94371840);   // g1p1 - g1p0
  const size_t G2_ZOFF = (size_t)(144703488 - 69206016);   // cpre1 - cpre0

  // fused front casts: x, Wq, Wkv, Wuv (one launch) + Wuk cast-transpose
  cast4_k<<<13824, 256, 0, stream>>>(x, xb, Wq, wbuf, Wkv, wkvb, Wuv, wuvb);
  castT_f2b_k<<<dim3(16, 48), 256, 0, stream>>>(Wuk, wukT, 3072, 1024);

  // 1. absorbed_k = Wq @ Wuk  split-K x2: M=3072 N=1024 K=2x1536 -> fp32 x2
  gemm_bf16<0, false><<<dim3(8, 24, 2), 256, 0, stream>>>(
      wbuf, wukT, nullptr, g1p0, nullptr, 3072, 1024, 1536, 3072, 3072,
      G1_ZOFF);
  //    fixup: akb = f2b(g1p0 + g1p1)
  sum_cast_k<<<1536, 256, 0, stream>>>(g1p0, g1p1, akb);
  // Wout cast reuses wbuf after G1 (serial stream)
  cast_f2b_k<<<4608, 256, 0, stream>>>(Wout, wbuf);
  // 2. c_pre split-K x2: M=4096 N=1024 K=2x1536 -> fp32 partials
  gemm_bf16<0, false><<<dim3(8, 32, 2), 256, 0, stream>>>(
      xb, wkvb, nullptr, cpre0, nullptr, 4096, 1024, 1536, 3072, 3072,
      G2_ZOFF);
  // 3. LayerNorm(cpre0+cpre1) -> ckv (fp32 output) + ckvb (bf16)
  ln_k<<<4096, 256, 0, stream>>>(cpre0, cpre1, lng, lnb, ckv32, ckvb);
  // 4+5 fused: [v|k] = ckv @ [Wuv; absorbed_k]^T   M=4096 N=6144 K=1024
  //    cols 0-3071 -> vT scatter (Cout2), cols 3072-6143 -> kfull (Cout)
  gemm_bf16<3, false><<<dim3(48, 32), 256, 0, stream>>>(
      ckvb, wuvb, nullptr, kfullb, vTb, 4096, 6144, 1024, 1024, 1024, 0);
  // 6. flash attention -> ctx
  attn_mfma<<<1024, 256, 0, stream>>>(xb, kfullb, vTb, ctxb);
  // 7. out = ctx @ Wout^T + b_out       M=4096 N=3072 K=3072 -> fp32
  gemm_bf16<0, true><<<dim3(24, 32), 256, 0, stream>>>(
      ctxb, wbuf, bout, out, nullptr, 4096, 3072, 3072, 3072, 3072, 0);
}